// Round 20
// baseline (695.299 us; speedup 1.0000x reference)
//
#include <hip/hip_runtime.h>
#include <hip/hip_bf16.h>

#define N_NODES 100000
#define N_EDGES 6400000
#define BROW 24    // bf16 row: 24 elems = 48B packed
#define PROW 8     // fp8 P-table row: 8 u32 = 32B; N_NODES+1 rows (last = zero sentinel)
#define BUCKET_SIZE 256
#define N_BUCKETS ((N_NODES + BUCKET_SIZE - 1) / BUCKET_SIZE)  // 391
#define BUCKET_CAP 19456   // csr entries/bucket: mean 16384 + per-row 8-pad (mean ~1024) + 8-sigma margin
#define STAGE_CAP 22528    // stage entries/bucket incl. per-(block,bucket) line padding
#define SENT 0xFFFFFFFFu
#define STAGE_BLOCKS 512
#define CHUNK ((N_EDGES + STAGE_BLOCKS - 1) / STAGE_BLOCKS)    // 12500 (mult of 4)
#define ENC_CHUNKS 4
#define K_PER 60            // 240 / ENC_CHUNKS

typedef float floatx2 __attribute__((ext_vector_type(2)));

__device__ __forceinline__ unsigned short f2bf(float f) {
    unsigned u = __float_as_uint(f);
    unsigned r = (u + 0x7fffu + ((u >> 16) & 1u)) >> 16;  // RNE
    return (unsigned short)r;
}

__device__ __forceinline__ unsigned pack_fp8_4(float a, float b, float c, float d) {
    int w = __builtin_amdgcn_cvt_pk_fp8_f32(a, b, 0, false);
    w = __builtin_amdgcn_cvt_pk_fp8_f32(c, d, w, true);
    return (unsigned)w;
}

#define DEC4(w, arr, j) { \
    floatx2 lo_ = __builtin_amdgcn_cvt_pk_f32_fp8((int)(w), false); \
    floatx2 hi_ = __builtin_amdgcn_cvt_pk_f32_fp8((int)(w), true);  \
    arr[j] += lo_.x; arr[(j)+1] += lo_.y; arr[(j)+2] += hi_.x; arr[(j)+3] += hi_.y; }

#define SET2(u, arr, j) { arr[j] = __uint_as_float((u) << 16); arr[(j)+1] = __uint_as_float((u) & 0xffff0000u); }
#define ADD2(u, arr, j) { arr[j] += __uint_as_float((u) << 16); arr[(j)+1] += __uint_as_float((u) & 0xffff0000u); }

// gather one neighbor's fp8 row and accumulate
#define GATHER1(sidx, acc) { \
    const uint4* rp_ = (const uint4*)(Ptab + (size_t)(sidx) * PROW); \
    uint4 A_ = rp_[0]; \
    uint2 B_ = ((const uint2*)rp_)[2]; \
    DEC4(A_.x, acc, 0)  DEC4(A_.y, acc, 4)  DEC4(A_.z, acc, 8) \
    DEC4(A_.w, acc,12)  DEC4(B_.x, acc,16)  DEC4(B_.y, acc,20) }

// ---------------- prep: transpose w1 [32][240]->[240][32] + zero cursor ----------------
__global__ __launch_bounds__(256) void k_prep(
    const float* __restrict__ w1, float* __restrict__ w1t, int* __restrict__ cursor)
{
    int tid = blockIdx.x * blockDim.x + threadIdx.x;
    if (tid < 32 * 240) {
        int k = tid >> 5, i = tid & 31;
        w1t[tid] = w1[i * 240 + k];
    }
    if (tid < N_BUCKETS * 16) cursor[tid] = 0;
}

// ---------------- CSR stage: LDS-staged, full-line single-shot global writes ----------------
__global__ __launch_bounds__(256) void k_stage1(
    const int* __restrict__ src, const int* __restrict__ dst,
    int* __restrict__ cursor, unsigned* __restrict__ stage)
{
    __shared__ int cnt[N_BUCKETS];
    __shared__ int bse[N_BUCKETS];
    __shared__ int lof[N_BUCKETS];
    __shared__ int cur[N_BUCKETS];
    __shared__ int ps[512];
    __shared__ unsigned sbuf[CHUNK];        // 50KB
    int t = threadIdx.x;
    int e0 = blockIdx.x * CHUNK;
    int e1 = min(e0 + CHUNK, N_EDGES);

    for (int i = t; i < N_BUCKETS; i += 256) cnt[i] = 0;
    __syncthreads();
    // pass 1: count (int4 streams)
    for (int e = e0 + 4 * t; e < e1; e += 1024) {
        int4 d4 = *(const int4*)(dst + e);
        atomicAdd(&cnt[d4.x >> 8], 1);
        atomicAdd(&cnt[d4.y >> 8], 1);
        atomicAdd(&cnt[d4.z >> 8], 1);
        atomicAdd(&cnt[d4.w >> 8], 1);
    }
    __syncthreads();
    for (int i = t; i < N_BUCKETS; i += 256) {
        int c = cnt[i];
        int c16 = (c + 15) & ~15;
        bse[i] = c16 ? atomicAdd(&cursor[i * 16], c16) : 0;
        cur[i] = 0;
    }
    ps[t]       = (t < N_BUCKETS) ? cnt[t] : 0;
    ps[t + 256] = (t + 256 < N_BUCKETS) ? cnt[t + 256] : 0;
    __syncthreads();
    for (int off = 1; off < 512; off <<= 1) {
        int a  = (t >= off) ? ps[t - off] : 0;
        int b2 = (t + 256 >= off) ? ps[t + 256 - off] : 0;
        __syncthreads();
        ps[t] += a;
        ps[t + 256] += b2;
        __syncthreads();
    }
    for (int i = t; i < N_BUCKETS; i += 256) lof[i] = ps[i] - cnt[i];
    __syncthreads();
    // pass 2: scatter into LDS (int4 streams)
    for (int e = e0 + 4 * t; e < e1; e += 1024) {
        int4 d4 = *(const int4*)(dst + e);
        int4 s4 = *(const int4*)(src + e);
#define PUT1(dd, ss) { int b_ = (dd) >> 8; int pos_ = atomicAdd(&cur[b_], 1); \
        sbuf[lof[b_] + pos_] = ((unsigned)((dd) & 255) << 17) | (unsigned)(ss); }
        PUT1(d4.x, s4.x)  PUT1(d4.y, s4.y)  PUT1(d4.z, s4.z)  PUT1(d4.w, s4.w)
#undef PUT1
    }
    __syncthreads();
    // copy-out: full 64B lines, written once
    int wid = t >> 6, lane = t & 63;
    for (int b = wid; b < N_BUCKETS; b += 4) {
        int c = cnt[b];
        int c16 = (c + 15) & ~15;
        unsigned* gp = stage + (size_t)b * STAGE_CAP + bse[b];
        const unsigned* lp = sbuf + lof[b];
        for (int j = lane; j < c16; j += 64)
            gp[j] = (j < c) ? lp[j] : SENT;
    }
}

// ---------------- MERGED: fillcsr (blocks <391) + enc split-K x4 partials (blocks >=391) ----------------
__global__ __launch_bounds__(256) void k_fill_enc(
    const unsigned* __restrict__ stage, const int* __restrict__ cursor,
    int* __restrict__ csr, int* __restrict__ deg,
    float* __restrict__ recip, int* __restrict__ row_ptr,
    const float* __restrict__ x,
    const float* __restrict__ w1t, const float* __restrict__ b1,
    const float* __restrict__ w2,
    unsigned short* __restrict__ pb0, unsigned short* __restrict__ pb1,
    unsigned short* __restrict__ pb2, unsigned short* __restrict__ pb3)
{
    __shared__ int dl[BUCKET_SIZE];
    __shared__ int s[BUCKET_SIZE];
    __shared__ int fcur[BUCKET_SIZE];
    int t = threadIdx.x;

    if (blockIdx.x < N_BUCKETS) {
        // ---- fillcsr body (uint4 stage scans; rows 8-padded with sentinel neighbor) ----
        int b = blockIdx.x;
        int ne = cursor[b * 16];           // multiple of 16
        const unsigned* sp = stage + (size_t)b * STAGE_CAP;

        dl[t] = 0;
        __syncthreads();
        for (int i = 4 * t; i < ne; i += 1024) {
            uint4 v4 = *(const uint4*)(sp + i);
            if (v4.x != SENT) atomicAdd(&dl[v4.x >> 17], 1);
            if (v4.y != SENT) atomicAdd(&dl[v4.y >> 17], 1);
            if (v4.z != SENT) atomicAdd(&dl[v4.z >> 17], 1);
            if (v4.w != SENT) atomicAdd(&dl[v4.w >> 17], 1);
        }
        __syncthreads();
        int d = dl[t];
        int d8 = (d + 7) & ~7;             // 8-aligned row length (32B-aligned start, deep-MLP gather)
        s[t] = d8;
        __syncthreads();
        for (int off = 1; off < 256; off <<= 1) {
            int v = (t >= off) ? s[t - off] : 0;
            __syncthreads();
            s[t] += v;
            __syncthreads();
        }
        int excl = s[t] - d8;              // 8-aligned start
        fcur[t] = excl;
        int n = b * BUCKET_SIZE + t;
        if (n < N_NODES) {
            deg[n] = d;
            recip[n] = 1.0f / (float)max(d, 1);
            row_ptr[n] = b * BUCKET_CAP + excl;
        }
        __syncthreads();
        int* cb = csr + (size_t)b * BUCKET_CAP;
        for (int i = 4 * t; i < ne; i += 1024) {
            uint4 v4 = *(const uint4*)(sp + i);
#define PLACE1(vv) if ((vv) != SENT) { int slot_ = atomicAdd(&fcur[(vv) >> 17], 1); cb[slot_] = (int)((vv) & 0x1FFFFu); }
            PLACE1(v4.x)  PLACE1(v4.y)  PLACE1(v4.z)  PLACE1(v4.w)
#undef PLACE1
        }
        __syncthreads();
        if (n < N_NODES) {
            for (int j = d; j < d8; ++j) cb[excl + j] = N_NODES;  // zero fp8 row
        }
    } else {
        // ---- enc_part body (split-K x4, chunk wave-uniform; tree-dot breaks latency chain) ----
        int bid = blockIdx.x - N_BUCKETS;
        int nb = bid >> 2;
        int chunk = bid & 3;
        int n = nb * 256 + t;
        if (n >= N_NODES) return;

        float xr[32];
        const float4* xv = (const float4*)(x + (size_t)n * 32);
#pragma unroll
        for (int i = 0; i < 8; ++i) {
            float4 v = xv[i];
            xr[4*i+0] = v.x; xr[4*i+1] = v.y; xr[4*i+2] = v.z; xr[4*i+3] = v.w;
        }
        float acc[24];
#pragma unroll
        for (int j = 0; j < 24; ++j) acc[j] = 0.f;

        int k0 = chunk * K_PER;
        for (int k = k0; k < k0 + K_PER; ++k) {
            const float4* wr = (const float4*)(w1t + k * 32);
            float tq[8];
#pragma unroll
            for (int q = 0; q < 8; ++q) {
                float4 w = wr[q];
                tq[q] = xr[4*q+0] * w.x + xr[4*q+1] * w.y
                      + xr[4*q+2] * w.z + xr[4*q+3] * w.w;
            }
            float tt = b1[k] + (((tq[0] + tq[1]) + (tq[2] + tq[3]))
                             +  ((tq[4] + tq[5]) + (tq[6] + tq[7])));
            tt = fmaxf(tt, 0.f);
            const float* w2r = w2 + k * 24;
#pragma unroll
            for (int j = 0; j < 24; ++j) acc[j] += tt * w2r[j];
        }
        unsigned wb[12];
#pragma unroll
        for (int j = 0; j < 24; ++j) {
            if (j & 1) wb[j >> 1] |= (unsigned)f2bf(acc[j]) << 16;
            else       wb[j >> 1]  = (unsigned)f2bf(acc[j]);
        }
        unsigned short* pb = (chunk == 0) ? pb0 : (chunk == 1) ? pb1 : (chunk == 2) ? pb2 : pb3;
        uint4* ob = (uint4*)(pb + (size_t)n * BROW);
#pragma unroll
        for (int q = 0; q < 3; ++q)
            ob[q] = make_uint4(wb[4*q], wb[4*q+1], wb[4*q+2], wb[4*q+3]);
    }
}

// ---------------- fused enc-finalize (4 partials) + layer1 xform (bl folded into Q) ----------------
__global__ __launch_bounds__(256) void k_encfin_xform(
    const unsigned short* __restrict__ pb0, const unsigned short* __restrict__ pb1,
    const unsigned short* __restrict__ pb2, const unsigned short* __restrict__ pb3,
    const float* __restrict__ b2,
    const float* __restrict__ wl, const float* __restrict__ wr,
    const float* __restrict__ bl,
    unsigned* __restrict__ Ptab, float* __restrict__ Qtab)
{
    int n = blockIdx.x * blockDim.x + threadIdx.x;
    if (n >= N_NODES) return;
    float h[24];
    {
        const uint4* hp = (const uint4*)(pb0 + (size_t)n * BROW);
        uint4 A = hp[0], B = hp[1], C = hp[2];
        SET2(A.x, h, 0)  SET2(A.y, h, 2)  SET2(A.z, h, 4)  SET2(A.w, h, 6)
        SET2(B.x, h, 8)  SET2(B.y, h,10)  SET2(B.z, h,12)  SET2(B.w, h,14)
        SET2(C.x, h,16)  SET2(C.y, h,18)  SET2(C.z, h,20)  SET2(C.w, h,22)
    }
    const unsigned short* pbs[3] = { pb1, pb2, pb3 };
#pragma unroll
    for (int c = 0; c < 3; ++c) {
        const uint4* hp = (const uint4*)(pbs[c] + (size_t)n * BROW);
        uint4 A = hp[0], B = hp[1], C = hp[2];
        ADD2(A.x, h, 0)  ADD2(A.y, h, 2)  ADD2(A.z, h, 4)  ADD2(A.w, h, 6)
        ADD2(B.x, h, 8)  ADD2(B.y, h,10)  ADD2(B.z, h,12)  ADD2(B.w, h,14)
        ADD2(C.x, h,16)  ADD2(C.y, h,18)  ADD2(C.z, h,20)  ADD2(C.w, h,22)
    }
#pragma unroll
    for (int j = 0; j < 24; ++j) h[j] = fmaxf(h[j] + b2[j], 0.f);

    float p[24], q[24];
#pragma unroll
    for (int j = 0; j < 24; ++j) { p[j] = 0.f; q[j] = bl[j]; }
#pragma unroll
    for (int k = 0; k < 24; ++k) {
        float hk = h[k];
#pragma unroll
        for (int j = 0; j < 24; ++j) {
            p[j] += hk * wl[k * 24 + j];
            q[j] += hk * wr[k * 24 + j];
        }
    }
    unsigned w8[6];
#pragma unroll
    for (int c = 0; c < 6; ++c)
        w8[c] = pack_fp8_4(p[4*c], p[4*c+1], p[4*c+2], p[4*c+3]);
    uint4* ob = (uint4*)(Ptab + (size_t)n * PROW);
    ob[0] = make_uint4(w8[0], w8[1], w8[2], w8[3]);
    ob[1] = make_uint4(w8[4], w8[5], 0u, 0u);
    float4* qb = (float4*)(Qtab + (size_t)n * 24);
#pragma unroll
    for (int c = 0; c < 6; ++c)
        qb[c] = make_float4(q[4*c], q[4*c+1], q[4*c+2], q[4*c+3]);
    if (n == 0) {   // zero sentinel row
        uint4* zb = (uint4*)(Ptab + (size_t)N_NODES * PROW);
        zb[0] = make_uint4(0u,0u,0u,0u);
        zb[1] = make_uint4(0u,0u,0u,0u);
    }
}

// ---------------- xform (layers 2,3), bl folded into Q ----------------
__global__ __launch_bounds__(256) void k_xform(
    const unsigned short* __restrict__ hin,
    const float* __restrict__ wl, const float* __restrict__ wr,
    const float* __restrict__ bl,
    unsigned* __restrict__ Ptab, float* __restrict__ Qtab)
{
    int n = blockIdx.x * blockDim.x + threadIdx.x;
    if (n >= N_NODES) return;
    float h[24];
    {
        const uint4* hp = (const uint4*)(hin + (size_t)n * BROW);
        uint4 A = hp[0], B = hp[1], C = hp[2];
        SET2(A.x, h, 0)  SET2(A.y, h, 2)  SET2(A.z, h, 4)  SET2(A.w, h, 6)
        SET2(B.x, h, 8)  SET2(B.y, h,10)  SET2(B.z, h,12)  SET2(B.w, h,14)
        SET2(C.x, h,16)  SET2(C.y, h,18)  SET2(C.z, h,20)  SET2(C.w, h,22)
    }
    float p[24], q[24];
#pragma unroll
    for (int j = 0; j < 24; ++j) { p[j] = 0.f; q[j] = bl[j]; }
#pragma unroll
    for (int k = 0; k < 24; ++k) {
        float hk = h[k];
#pragma unroll
        for (int j = 0; j < 24; ++j) {
            p[j] += hk * wl[k * 24 + j];
            q[j] += hk * wr[k * 24 + j];
        }
    }
    unsigned w8[6];
#pragma unroll
    for (int c = 0; c < 6; ++c)
        w8[c] = pack_fp8_4(p[4*c], p[4*c+1], p[4*c+2], p[4*c+3]);
    uint4* ob = (uint4*)(Ptab + (size_t)n * PROW);
    ob[0] = make_uint4(w8[0], w8[1], w8[2], w8[3]);
    ob[1] = make_uint4(w8[4], w8[5], 0u, 0u);
    float4* qb = (float4*)(Qtab + (size_t)n * 24);
#pragma unroll
    for (int c = 0; c < 6; ++c)
        qb[c] = make_float4(q[4*c], q[4*c+1], q[4*c+2], q[4*c+3]);
    if (n == 0) {
        uint4* zb = (uint4*)(Ptab + (size_t)N_NODES * PROW);
        zb[0] = make_uint4(0u,0u,0u,0u);
        zb[1] = make_uint4(0u,0u,0u,0u);
    }
}

// ---------------- agg: 8 lanes/node, 8 neighbors per lane-iteration (deep MLP) ----------------
template <bool RELU>
__global__ __launch_bounds__(256, 4) void k_agg(
    const unsigned* __restrict__ Ptab, const float* __restrict__ Qtab,
    const int* __restrict__ row_ptr, const int* __restrict__ deg,
    const float* __restrict__ recip, const int* __restrict__ csr,
    unsigned short* __restrict__ houtb)
{
    int gt = blockIdx.x * blockDim.x + threadIdx.x;
    int n = gt >> 3, g = gt & 7;
    if (n >= N_NODES) return;
    int start = row_ptr[n];
    int cnt8 = (deg[n] + 7) & ~7;

    float acc[24];
#pragma unroll
    for (int j = 0; j < 24; ++j) acc[j] = 0.f;

    for (int i0 = 8 * g; i0 < cnt8; i0 += 64) {
        int4 sa = *(const int4*)(csr + start + i0);
        int4 sb = *(const int4*)(csr + start + i0 + 4);
        GATHER1(sa.x, acc)  GATHER1(sa.y, acc)  GATHER1(sa.z, acc)  GATHER1(sa.w, acc)
        GATHER1(sb.x, acc)  GATHER1(sb.y, acc)  GATHER1(sb.z, acc)  GATHER1(sb.w, acc)
    }
#pragma unroll
    for (int m = 1; m <= 4; m <<= 1)
#pragma unroll
        for (int j = 0; j < 24; ++j) acc[j] += __shfl_xor(acc[j], m, 64);

    if (g < 3) {
        float rc = recip[n];
        const float4* qb = (const float4*)(Qtab + (size_t)n * 24 + g * 8);
        float4 q0 = qb[0], q1 = qb[1];
        float qv[8] = {q0.x, q0.y, q0.z, q0.w, q1.x, q1.y, q1.z, q1.w};
        unsigned wb[4];
#pragma unroll
        for (int jj = 0; jj < 8; ++jj) {
            int j = g * 8 + jj;
            float v = acc[j] * rc + qv[jj];
            if (RELU) v = fmaxf(v, 0.f);
            if (jj & 1) wb[jj >> 1] |= (unsigned)f2bf(v) << 16;
            else        wb[jj >> 1]  = (unsigned)f2bf(v);
        }
        ((uint4*)(houtb + (size_t)n * BROW))[g] = make_uint4(wb[0], wb[1], wb[2], wb[3]);
    }
}

// ---------------- agg3: 8 lanes/node, fp32 output, no relu ----------------
__global__ __launch_bounds__(256, 4) void k_agg3(
    const unsigned* __restrict__ Ptab, const float* __restrict__ Qtab,
    const int* __restrict__ row_ptr, const int* __restrict__ deg,
    const float* __restrict__ recip, const int* __restrict__ csr,
    float* __restrict__ o3)
{
    int gt = blockIdx.x * blockDim.x + threadIdx.x;
    int n = gt >> 3, g = gt & 7;
    if (n >= N_NODES) return;
    int start = row_ptr[n];
    int cnt8 = (deg[n] + 7) & ~7;

    float acc[24];
#pragma unroll
    for (int j = 0; j < 24; ++j) acc[j] = 0.f;

    for (int i0 = 8 * g; i0 < cnt8; i0 += 64) {
        int4 sa = *(const int4*)(csr + start + i0);
        int4 sb = *(const int4*)(csr + start + i0 + 4);
        GATHER1(sa.x, acc)  GATHER1(sa.y, acc)  GATHER1(sa.z, acc)  GATHER1(sa.w, acc)
        GATHER1(sb.x, acc)  GATHER1(sb.y, acc)  GATHER1(sb.z, acc)  GATHER1(sb.w, acc)
    }
#pragma unroll
    for (int m = 1; m <= 4; m <<= 1)
#pragma unroll
        for (int j = 0; j < 24; ++j) acc[j] += __shfl_xor(acc[j], m, 64);

    if (g < 3) {
        float rc = recip[n];
        const float4* qb = (const float4*)(Qtab + (size_t)n * 24 + g * 8);
        float4 q0 = qb[0], q1 = qb[1];
        float qv[8] = {q0.x, q0.y, q0.z, q0.w, q1.x, q1.y, q1.z, q1.w};
        float ov[8];
#pragma unroll
        for (int jj = 0; jj < 8; ++jj)
            ov[jj] = acc[g * 8 + jj] * rc + qv[jj];
        float4* op = (float4*)(o3 + (size_t)n * 24 + g * 8);
        op[0] = make_float4(ov[0], ov[1], ov[2], ov[3]);
        op[1] = make_float4(ov[4], ov[5], ov[6], ov[7]);
    }
}

// ---------------- decoder ----------------
__global__ __launch_bounds__(256) void k_decoder(
    const float* __restrict__ o3,
    const float* __restrict__ w1, const float* __restrict__ b1,
    const float* __restrict__ w2, const float* __restrict__ b2,
    float* __restrict__ out)
{
    int n = blockIdx.x * blockDim.x + threadIdx.x;
    if (n >= N_NODES) return;
    float h[24];
    const float4* hv = (const float4*)(o3 + (size_t)n * 24);
#pragma unroll
    for (int q = 0; q < 6; ++q) {
        float4 v = hv[q];
        h[4*q+0] = v.x; h[4*q+1] = v.y; h[4*q+2] = v.z; h[4*q+3] = v.w;
    }
    float acc[12];
#pragma unroll
    for (int j = 0; j < 12; ++j) acc[j] = b2[j];
    for (int k = 0; k < 120; ++k) {
        float t = b1[k];
#pragma unroll
        for (int i = 0; i < 24; ++i) t += h[i] * w1[i * 120 + k];
        t = fmaxf(t, 0.f);
#pragma unroll
        for (int j = 0; j < 12; ++j) acc[j] += t * w2[k * 12 + j];
    }
    float* o = out + (size_t)n * 12;
#pragma unroll
    for (int j = 0; j < 12; ++j) o[j] = acc[j];
}

// ---------------- host launch ----------------
static inline size_t align_up(size_t v, size_t a) { return (v + a - 1) & ~(a - 1); }

extern "C" void kernel_launch(void* const* d_in, const int* in_sizes, int n_in,
                              void* d_out, int out_size, void* d_ws, size_t ws_size,
                              hipStream_t stream)
{
    (void)in_sizes; (void)n_in; (void)out_size; (void)ws_size;

    const float* x    = (const float*)d_in[0];
    const int*  edge  = (const int*)d_in[1];
    const int*  esrc  = edge;
    const int*  edst  = edge + N_EDGES;
    const float* enc_w1 = (const float*)d_in[2];
    const float* enc_b1 = (const float*)d_in[3];
    const float* enc_w2 = (const float*)d_in[4];
    const float* enc_b2 = (const float*)d_in[5];
    const float* s1_wl = (const float*)d_in[6];
    const float* s1_bl = (const float*)d_in[7];
    const float* s1_wr = (const float*)d_in[8];
    const float* s2_wl = (const float*)d_in[9];
    const float* s2_bl = (const float*)d_in[10];
    const float* s2_wr = (const float*)d_in[11];
    const float* s3_wl = (const float*)d_in[12];
    const float* s3_bl = (const float*)d_in[13];
    const float* s3_wr = (const float*)d_in[14];
    const float* dec_w1 = (const float*)d_in[15];
    const float* dec_b1 = (const float*)d_in[16];
    const float* dec_w2 = (const float*)d_in[17];
    const float* dec_b2 = (const float*)d_in[18];
    float* out = (float*)d_out;

    // workspace carve
    char* base = (char*)d_ws;
    size_t off = 0;
    auto carve = [&](size_t bytes) { size_t o = off; off = align_up(off + bytes, 256); return (void*)(base + o); };
    // stage region (35.2MB); dead after k_fill_enc -> o3 (9.6MB) aliases it
    char* stage_region = (char*)carve((size_t)N_BUCKETS * STAGE_CAP * sizeof(unsigned));
    unsigned* stage = (unsigned*)stage_region;
    float* o3       = (float*)stage_region;
    int*   csr      = (int*)carve((size_t)N_BUCKETS * BUCKET_CAP * sizeof(int));          // 30.4MB
    unsigned* Ptab  = (unsigned*)carve((size_t)(N_NODES + 1) * PROW * sizeof(unsigned));  // 3.2MB
    float* Qtab     = (float*)carve((size_t)N_NODES * 24 * sizeof(float));                // 9.6MB
    unsigned short* h0b = (unsigned short*)carve((size_t)N_NODES * BROW * sizeof(unsigned short));
    unsigned short* h1b = (unsigned short*)carve((size_t)N_NODES * BROW * sizeof(unsigned short));
    unsigned short* pb2 = (unsigned short*)carve((size_t)N_NODES * BROW * sizeof(unsigned short));
    unsigned short* pb3 = (unsigned short*)carve((size_t)N_NODES * BROW * sizeof(unsigned short));
    int*   deg     = (int*)  carve((size_t)N_NODES * sizeof(int));
    float* recip   = (float*)carve((size_t)N_NODES * sizeof(float));
    int*   row_ptr = (int*)  carve((size_t)N_NODES * sizeof(int));
    int*   cursor  = (int*)  carve((size_t)N_BUCKETS * 16 * sizeof(int));
    float* w1t     = (float*)carve((size_t)240 * 32 * sizeof(float));

    const int NB_N = (N_NODES + 255) / 256;      // 391
    const int NB8  = (N_NODES * 8 + 255) / 256;  // 3125

    k_prep<<<30, 256, 0, stream>>>(enc_w1, w1t, cursor);
    k_stage1<<<STAGE_BLOCKS, 256, 0, stream>>>(esrc, edst, cursor, stage);

    // MERGED: fillcsr (391 blocks) + encoder split-K x4 partials (1564 blocks)
    k_fill_enc<<<NB_N * 5, 256, 0, stream>>>(
        stage, cursor, csr, deg, recip, row_ptr,
        x, w1t, enc_b1, enc_w2, h0b, h1b, pb2, pb3);

    // fused encoder-finalize (4 partials) + layer1 xform (bl folded into Q)
    k_encfin_xform<<<NB_N, 256, 0, stream>>>(h0b, h1b, pb2, pb3, enc_b2, s1_wl, s1_wr, s1_bl, Ptab, Qtab);
    k_agg<true><<<NB8, 256, 0, stream>>>(Ptab, Qtab, row_ptr, deg, recip, csr, h1b);
    // layer 2
    k_xform<<<NB_N, 256, 0, stream>>>(h1b, s2_wl, s2_wr, s2_bl, Ptab, Qtab);
    k_agg<true><<<NB8, 256, 0, stream>>>(Ptab, Qtab, row_ptr, deg, recip, csr, h0b);
    // layer 3 (fp32 out, o3 aliases dead stage region) + decoder
    k_xform<<<NB_N, 256, 0, stream>>>(h0b, s3_wl, s3_wr, s3_bl, Ptab, Qtab);
    k_agg3<<<NB8, 256, 0, stream>>>(Ptab, Qtab, row_ptr, deg, recip, csr, o3);
    k_decoder<<<NB_N, 256, 0, stream>>>(o3, dec_w1, dec_b1, dec_w2, dec_b2, out);
}

// Round 21
// 434.160 us; speedup vs baseline: 1.6015x; 1.6015x over previous
//
#include <hip/hip_runtime.h>
#include <hip/hip_bf16.h>

#define N_NODES 100000
#define N_EDGES 6400000
#define BROW 24    // bf16 row: 24 elems = 48B packed
#define PROW 8     // fp8 P-table row: 8 u32 = 32B; N_NODES+1 rows (last = zero sentinel)
#define BUCKET_SIZE 256
#define N_BUCKETS ((N_NODES + BUCKET_SIZE - 1) / BUCKET_SIZE)  // 391
#define BUCKET_CAP 17920   // csr entries/bucket: mean 16384 + per-row 4-pad + margin
#define STAGE_CAP 22528    // stage entries/bucket incl. per-(block,bucket) line padding
#define SENT 0xFFFFFFFFu
#define STAGE_BLOCKS 512
#define CHUNK ((N_EDGES + STAGE_BLOCKS - 1) / STAGE_BLOCKS)    // 12500 (mult of 4)
#define ENC_CHUNKS 4
#define K_PER 60            // 240 / ENC_CHUNKS

typedef float floatx2 __attribute__((ext_vector_type(2)));

__device__ __forceinline__ unsigned short f2bf(float f) {
    unsigned u = __float_as_uint(f);
    unsigned r = (u + 0x7fffu + ((u >> 16) & 1u)) >> 16;  // RNE
    return (unsigned short)r;
}

__device__ __forceinline__ unsigned pack_fp8_4(float a, float b, float c, float d) {
    int w = __builtin_amdgcn_cvt_pk_fp8_f32(a, b, 0, false);
    w = __builtin_amdgcn_cvt_pk_fp8_f32(c, d, w, true);
    return (unsigned)w;
}

#define DEC4(w, arr, j) { \
    floatx2 lo_ = __builtin_amdgcn_cvt_pk_f32_fp8((int)(w), false); \
    floatx2 hi_ = __builtin_amdgcn_cvt_pk_f32_fp8((int)(w), true);  \
    arr[j] += lo_.x; arr[(j)+1] += lo_.y; arr[(j)+2] += hi_.x; arr[(j)+3] += hi_.y; }

#define SET2(u, arr, j) { arr[j] = __uint_as_float((u) << 16); arr[(j)+1] = __uint_as_float((u) & 0xffff0000u); }
#define ADD2(u, arr, j) { arr[j] += __uint_as_float((u) << 16); arr[(j)+1] += __uint_as_float((u) & 0xffff0000u); }

// gather one neighbor's fp8 row and accumulate
#define GATHER1(sidx, acc) { \
    const uint4* rp_ = (const uint4*)(Ptab + (size_t)(sidx) * PROW); \
    uint4 A_ = rp_[0]; \
    uint2 B_ = ((const uint2*)rp_)[2]; \
    DEC4(A_.x, acc, 0)  DEC4(A_.y, acc, 4)  DEC4(A_.z, acc, 8) \
    DEC4(A_.w, acc,12)  DEC4(B_.x, acc,16)  DEC4(B_.y, acc,20) }

// ---------------- prep: transpose w1 [32][240]->[240][32] + zero cursor ----------------
__global__ __launch_bounds__(256) void k_prep(
    const float* __restrict__ w1, float* __restrict__ w1t, int* __restrict__ cursor)
{
    int tid = blockIdx.x * blockDim.x + threadIdx.x;
    if (tid < 32 * 240) {
        int k = tid >> 5, i = tid & 31;
        w1t[tid] = w1[i * 240 + k];
    }
    if (tid < N_BUCKETS * 16) cursor[tid] = 0;
}

// ---------------- CSR stage: LDS-staged, full-line single-shot global writes ----------------
__global__ __launch_bounds__(256) void k_stage1(
    const int* __restrict__ src, const int* __restrict__ dst,
    int* __restrict__ cursor, unsigned* __restrict__ stage)
{
    __shared__ int cnt[N_BUCKETS];
    __shared__ int bse[N_BUCKETS];
    __shared__ int lof[N_BUCKETS];
    __shared__ int cur[N_BUCKETS];
    __shared__ int ps[512];
    __shared__ unsigned sbuf[CHUNK];        // 50KB
    int t = threadIdx.x;
    int e0 = blockIdx.x * CHUNK;
    int e1 = min(e0 + CHUNK, N_EDGES);

    for (int i = t; i < N_BUCKETS; i += 256) cnt[i] = 0;
    __syncthreads();
    // pass 1: count (int4 streams)
    for (int e = e0 + 4 * t; e < e1; e += 1024) {
        int4 d4 = *(const int4*)(dst + e);
        atomicAdd(&cnt[d4.x >> 8], 1);
        atomicAdd(&cnt[d4.y >> 8], 1);
        atomicAdd(&cnt[d4.z >> 8], 1);
        atomicAdd(&cnt[d4.w >> 8], 1);
    }
    __syncthreads();
    for (int i = t; i < N_BUCKETS; i += 256) {
        int c = cnt[i];
        int c16 = (c + 15) & ~15;
        bse[i] = c16 ? atomicAdd(&cursor[i * 16], c16) : 0;
        cur[i] = 0;
    }
    ps[t]       = (t < N_BUCKETS) ? cnt[t] : 0;
    ps[t + 256] = (t + 256 < N_BUCKETS) ? cnt[t + 256] : 0;
    __syncthreads();
    for (int off = 1; off < 512; off <<= 1) {
        int a  = (t >= off) ? ps[t - off] : 0;
        int b2 = (t + 256 >= off) ? ps[t + 256 - off] : 0;
        __syncthreads();
        ps[t] += a;
        ps[t + 256] += b2;
        __syncthreads();
    }
    for (int i = t; i < N_BUCKETS; i += 256) lof[i] = ps[i] - cnt[i];
    __syncthreads();
    // pass 2: scatter into LDS (int4 streams)
    for (int e = e0 + 4 * t; e < e1; e += 1024) {
        int4 d4 = *(const int4*)(dst + e);
        int4 s4 = *(const int4*)(src + e);
#define PUT1(dd, ss) { int b_ = (dd) >> 8; int pos_ = atomicAdd(&cur[b_], 1); \
        sbuf[lof[b_] + pos_] = ((unsigned)((dd) & 255) << 17) | (unsigned)(ss); }
        PUT1(d4.x, s4.x)  PUT1(d4.y, s4.y)  PUT1(d4.z, s4.z)  PUT1(d4.w, s4.w)
#undef PUT1
    }
    __syncthreads();
    // copy-out: full 64B lines, written once
    int wid = t >> 6, lane = t & 63;
    for (int b = wid; b < N_BUCKETS; b += 4) {
        int c = cnt[b];
        int c16 = (c + 15) & ~15;
        unsigned* gp = stage + (size_t)b * STAGE_CAP + bse[b];
        const unsigned* lp = sbuf + lof[b];
        for (int j = lane; j < c16; j += 64)
            gp[j] = (j < c) ? lp[j] : SENT;
    }
}

// ---------------- MERGED: fillcsr (blocks <391) + enc split-K x4 partials (blocks >=391) ----------------
__global__ __launch_bounds__(256) void k_fill_enc(
    const unsigned* __restrict__ stage, const int* __restrict__ cursor,
    int* __restrict__ csr, int* __restrict__ deg,
    float* __restrict__ recip, int* __restrict__ row_ptr,
    const float* __restrict__ x,
    const float* __restrict__ w1t, const float* __restrict__ b1,
    const float* __restrict__ w2,
    unsigned short* __restrict__ pb0, unsigned short* __restrict__ pb1,
    unsigned short* __restrict__ pb2, unsigned short* __restrict__ pb3)
{
    __shared__ int dl[BUCKET_SIZE];
    __shared__ int s[BUCKET_SIZE];
    __shared__ int fcur[BUCKET_SIZE];
    int t = threadIdx.x;

    if (blockIdx.x < N_BUCKETS) {
        // ---- fillcsr body (uint4 stage scans; rows 4-padded with sentinel neighbor) ----
        int b = blockIdx.x;
        int ne = cursor[b * 16];           // multiple of 16
        const unsigned* sp = stage + (size_t)b * STAGE_CAP;

        dl[t] = 0;
        __syncthreads();
        for (int i = 4 * t; i < ne; i += 1024) {
            uint4 v4 = *(const uint4*)(sp + i);
            if (v4.x != SENT) atomicAdd(&dl[v4.x >> 17], 1);
            if (v4.y != SENT) atomicAdd(&dl[v4.y >> 17], 1);
            if (v4.z != SENT) atomicAdd(&dl[v4.z >> 17], 1);
            if (v4.w != SENT) atomicAdd(&dl[v4.w >> 17], 1);
        }
        __syncthreads();
        int d = dl[t];
        int d4 = (d + 3) & ~3;             // 16B-aligned row length
        s[t] = d4;
        __syncthreads();
        for (int off = 1; off < 256; off <<= 1) {
            int v = (t >= off) ? s[t - off] : 0;
            __syncthreads();
            s[t] += v;
            __syncthreads();
        }
        int excl = s[t] - d4;              // 4-aligned start
        fcur[t] = excl;
        int n = b * BUCKET_SIZE + t;
        if (n < N_NODES) {
            deg[n] = d;
            recip[n] = 1.0f / (float)max(d, 1);
            row_ptr[n] = b * BUCKET_CAP + excl;
        }
        __syncthreads();
        int* cb = csr + (size_t)b * BUCKET_CAP;
        for (int i = 4 * t; i < ne; i += 1024) {
            uint4 v4 = *(const uint4*)(sp + i);
#define PLACE1(vv) if ((vv) != SENT) { int slot_ = atomicAdd(&fcur[(vv) >> 17], 1); cb[slot_] = (int)((vv) & 0x1FFFFu); }
            PLACE1(v4.x)  PLACE1(v4.y)  PLACE1(v4.z)  PLACE1(v4.w)
#undef PLACE1
        }
        __syncthreads();
        if (n < N_NODES) {
            for (int j = d; j < d4; ++j) cb[excl + j] = N_NODES;  // zero fp8 row
        }
    } else {
        // ---- enc_part body (split-K x4, chunk wave-uniform; tree-dot breaks latency chain) ----
        int bid = blockIdx.x - N_BUCKETS;
        int nb = bid >> 2;
        int chunk = bid & 3;
        int n = nb * 256 + t;
        if (n >= N_NODES) return;

        float xr[32];
        const float4* xv = (const float4*)(x + (size_t)n * 32);
#pragma unroll
        for (int i = 0; i < 8; ++i) {
            float4 v = xv[i];
            xr[4*i+0] = v.x; xr[4*i+1] = v.y; xr[4*i+2] = v.z; xr[4*i+3] = v.w;
        }
        float acc[24];
#pragma unroll
        for (int j = 0; j < 24; ++j) acc[j] = 0.f;

        int k0 = chunk * K_PER;
        for (int k = k0; k < k0 + K_PER; ++k) {
            const float4* wr = (const float4*)(w1t + k * 32);
            float tq[8];
#pragma unroll
            for (int q = 0; q < 8; ++q) {
                float4 w = wr[q];
                tq[q] = xr[4*q+0] * w.x + xr[4*q+1] * w.y
                      + xr[4*q+2] * w.z + xr[4*q+3] * w.w;
            }
            float tt = b1[k] + (((tq[0] + tq[1]) + (tq[2] + tq[3]))
                             +  ((tq[4] + tq[5]) + (tq[6] + tq[7])));
            tt = fmaxf(tt, 0.f);
            const float* w2r = w2 + k * 24;
#pragma unroll
            for (int j = 0; j < 24; ++j) acc[j] += tt * w2r[j];
        }
        unsigned wb[12];
#pragma unroll
        for (int j = 0; j < 24; ++j) {
            if (j & 1) wb[j >> 1] |= (unsigned)f2bf(acc[j]) << 16;
            else       wb[j >> 1]  = (unsigned)f2bf(acc[j]);
        }
        unsigned short* pb = (chunk == 0) ? pb0 : (chunk == 1) ? pb1 : (chunk == 2) ? pb2 : pb3;
        uint4* ob = (uint4*)(pb + (size_t)n * BROW);
#pragma unroll
        for (int q = 0; q < 3; ++q)
            ob[q] = make_uint4(wb[4*q], wb[4*q+1], wb[4*q+2], wb[4*q+3]);
    }
}

// ---------------- fused enc-finalize (4 partials) + layer1 xform ----------------
__global__ __launch_bounds__(256) void k_encfin_xform(
    const unsigned short* __restrict__ pb0, const unsigned short* __restrict__ pb1,
    const unsigned short* __restrict__ pb2, const unsigned short* __restrict__ pb3,
    const float* __restrict__ b2,
    const float* __restrict__ wl, const float* __restrict__ wr,
    unsigned* __restrict__ Ptab, float* __restrict__ Qtab)
{
    int n = blockIdx.x * blockDim.x + threadIdx.x;
    if (n >= N_NODES) return;
    float h[24];
    {
        const uint4* hp = (const uint4*)(pb0 + (size_t)n * BROW);
        uint4 A = hp[0], B = hp[1], C = hp[2];
        SET2(A.x, h, 0)  SET2(A.y, h, 2)  SET2(A.z, h, 4)  SET2(A.w, h, 6)
        SET2(B.x, h, 8)  SET2(B.y, h,10)  SET2(B.z, h,12)  SET2(B.w, h,14)
        SET2(C.x, h,16)  SET2(C.y, h,18)  SET2(C.z, h,20)  SET2(C.w, h,22)
    }
    const unsigned short* pbs[3] = { pb1, pb2, pb3 };
#pragma unroll
    for (int c = 0; c < 3; ++c) {
        const uint4* hp = (const uint4*)(pbs[c] + (size_t)n * BROW);
        uint4 A = hp[0], B = hp[1], C = hp[2];
        ADD2(A.x, h, 0)  ADD2(A.y, h, 2)  ADD2(A.z, h, 4)  ADD2(A.w, h, 6)
        ADD2(B.x, h, 8)  ADD2(B.y, h,10)  ADD2(B.z, h,12)  ADD2(B.w, h,14)
        ADD2(C.x, h,16)  ADD2(C.y, h,18)  ADD2(C.z, h,20)  ADD2(C.w, h,22)
    }
#pragma unroll
    for (int j = 0; j < 24; ++j) h[j] = fmaxf(h[j] + b2[j], 0.f);

    float p[24], q[24];
#pragma unroll
    for (int j = 0; j < 24; ++j) { p[j] = 0.f; q[j] = 0.f; }
#pragma unroll
    for (int k = 0; k < 24; ++k) {
        float hk = h[k];
#pragma unroll
        for (int j = 0; j < 24; ++j) {
            p[j] += hk * wl[k * 24 + j];
            q[j] += hk * wr[k * 24 + j];
        }
    }
    unsigned w8[6];
#pragma unroll
    for (int c = 0; c < 6; ++c)
        w8[c] = pack_fp8_4(p[4*c], p[4*c+1], p[4*c+2], p[4*c+3]);
    uint4* ob = (uint4*)(Ptab + (size_t)n * PROW);
    ob[0] = make_uint4(w8[0], w8[1], w8[2], w8[3]);
    ob[1] = make_uint4(w8[4], w8[5], 0u, 0u);
    float4* qb = (float4*)(Qtab + (size_t)n * 24);
#pragma unroll
    for (int c = 0; c < 6; ++c)
        qb[c] = make_float4(q[4*c], q[4*c+1], q[4*c+2], q[4*c+3]);
    if (n == 0) {   // zero sentinel row
        uint4* zb = (uint4*)(Ptab + (size_t)N_NODES * PROW);
        zb[0] = make_uint4(0u,0u,0u,0u);
        zb[1] = make_uint4(0u,0u,0u,0u);
    }
}

// ---------------- xform (layers 2,3) ----------------
__global__ __launch_bounds__(256) void k_xform(
    const unsigned short* __restrict__ hin,
    const float* __restrict__ wl, const float* __restrict__ wr,
    unsigned* __restrict__ Ptab, float* __restrict__ Qtab)
{
    int n = blockIdx.x * blockDim.x + threadIdx.x;
    if (n >= N_NODES) return;
    float h[24];
    {
        const uint4* hp = (const uint4*)(hin + (size_t)n * BROW);
        uint4 A = hp[0], B = hp[1], C = hp[2];
        SET2(A.x, h, 0)  SET2(A.y, h, 2)  SET2(A.z, h, 4)  SET2(A.w, h, 6)
        SET2(B.x, h, 8)  SET2(B.y, h,10)  SET2(B.z, h,12)  SET2(B.w, h,14)
        SET2(C.x, h,16)  SET2(C.y, h,18)  SET2(C.z, h,20)  SET2(C.w, h,22)
    }
    float p[24], q[24];
#pragma unroll
    for (int j = 0; j < 24; ++j) { p[j] = 0.f; q[j] = 0.f; }
#pragma unroll
    for (int k = 0; k < 24; ++k) {
        float hk = h[k];
#pragma unroll
        for (int j = 0; j < 24; ++j) {
            p[j] += hk * wl[k * 24 + j];
            q[j] += hk * wr[k * 24 + j];
        }
    }
    unsigned w8[6];
#pragma unroll
    for (int c = 0; c < 6; ++c)
        w8[c] = pack_fp8_4(p[4*c], p[4*c+1], p[4*c+2], p[4*c+3]);
    uint4* ob = (uint4*)(Ptab + (size_t)n * PROW);
    ob[0] = make_uint4(w8[0], w8[1], w8[2], w8[3]);
    ob[1] = make_uint4(w8[4], w8[5], 0u, 0u);
    float4* qb = (float4*)(Qtab + (size_t)n * 24);
#pragma unroll
    for (int c = 0; c < 6; ++c)
        qb[c] = make_float4(q[4*c], q[4*c+1], q[4*c+2], q[4*c+3]);
    if (n == 0) {
        uint4* zb = (uint4*)(Ptab + (size_t)N_NODES * PROW);
        zb[0] = make_uint4(0u,0u,0u,0u);
        zb[1] = make_uint4(0u,0u,0u,0u);
    }
}

// ---------------- agg: int4 csr loads, fp8 gather, 8 lanes/node ----------------
template <bool RELU>
__global__ __launch_bounds__(256, 4) void k_agg(
    const unsigned* __restrict__ Ptab, const float* __restrict__ Qtab,
    const int* __restrict__ row_ptr, const int* __restrict__ deg,
    const float* __restrict__ recip, const int* __restrict__ csr,
    const float* __restrict__ bl,
    unsigned short* __restrict__ houtb)
{
    int gt = blockIdx.x * blockDim.x + threadIdx.x;
    int n = gt >> 3, g = gt & 7;
    if (n >= N_NODES) return;
    int start = row_ptr[n];
    int cnt4 = (deg[n] + 3) & ~3;

    float acc[24];
#pragma unroll
    for (int j = 0; j < 24; ++j) acc[j] = 0.f;

    for (int i0 = 4 * g; i0 < cnt4; i0 += 32) {
        int4 s4 = *(const int4*)(csr + start + i0);
        GATHER1(s4.x, acc)
        GATHER1(s4.y, acc)
        GATHER1(s4.z, acc)
        GATHER1(s4.w, acc)
    }
#pragma unroll
    for (int m = 1; m <= 4; m <<= 1)
#pragma unroll
        for (int j = 0; j < 24; ++j) acc[j] += __shfl_xor(acc[j], m, 64);

    if (g < 3) {
        float rc = recip[n];
        const float4* qb = (const float4*)(Qtab + (size_t)n * 24 + g * 8);
        float4 q0 = qb[0], q1 = qb[1];
        float qv[8] = {q0.x, q0.y, q0.z, q0.w, q1.x, q1.y, q1.z, q1.w};
        unsigned wb[4];
#pragma unroll
        for (int jj = 0; jj < 8; ++jj) {
            int j = g * 8 + jj;
            float v = acc[j] * rc + qv[jj] + bl[j];
            if (RELU) v = fmaxf(v, 0.f);
            if (jj & 1) wb[jj >> 1] |= (unsigned)f2bf(v) << 16;
            else        wb[jj >> 1]  = (unsigned)f2bf(v);
        }
        ((uint4*)(houtb + (size_t)n * BROW))[g] = make_uint4(wb[0], wb[1], wb[2], wb[3]);
    }
}

// ---------------- agg3: fp32 output, no relu ----------------
__global__ __launch_bounds__(256, 4) void k_agg3(
    const unsigned* __restrict__ Ptab, const float* __restrict__ Qtab,
    const int* __restrict__ row_ptr, const int* __restrict__ deg,
    const float* __restrict__ recip, const int* __restrict__ csr,
    const float* __restrict__ bl,
    float* __restrict__ o3)
{
    int gt = blockIdx.x * blockDim.x + threadIdx.x;
    int n = gt >> 3, g = gt & 7;
    if (n >= N_NODES) return;
    int start = row_ptr[n];
    int cnt4 = (deg[n] + 3) & ~3;

    float acc[24];
#pragma unroll
    for (int j = 0; j < 24; ++j) acc[j] = 0.f;

    for (int i0 = 4 * g; i0 < cnt4; i0 += 32) {
        int4 s4 = *(const int4*)(csr + start + i0);
        GATHER1(s4.x, acc)
        GATHER1(s4.y, acc)
        GATHER1(s4.z, acc)
        GATHER1(s4.w, acc)
    }
#pragma unroll
    for (int m = 1; m <= 4; m <<= 1)
#pragma unroll
        for (int j = 0; j < 24; ++j) acc[j] += __shfl_xor(acc[j], m, 64);

    if (g < 3) {
        float rc = recip[n];
        const float4* qb = (const float4*)(Qtab + (size_t)n * 24 + g * 8);
        float4 q0 = qb[0], q1 = qb[1];
        float qv[8] = {q0.x, q0.y, q0.z, q0.w, q1.x, q1.y, q1.z, q1.w};
        float ov[8];
#pragma unroll
        for (int jj = 0; jj < 8; ++jj)
            ov[jj] = acc[g * 8 + jj] * rc + qv[jj] + bl[g * 8 + jj];
        float4* op = (float4*)(o3 + (size_t)n * 24 + g * 8);
        op[0] = make_float4(ov[0], ov[1], ov[2], ov[3]);
        op[1] = make_float4(ov[4], ov[5], ov[6], ov[7]);
    }
}

// ---------------- decoder ----------------
__global__ __launch_bounds__(256) void k_decoder(
    const float* __restrict__ o3,
    const float* __restrict__ w1, const float* __restrict__ b1,
    const float* __restrict__ w2, const float* __restrict__ b2,
    float* __restrict__ out)
{
    int n = blockIdx.x * blockDim.x + threadIdx.x;
    if (n >= N_NODES) return;
    float h[24];
    const float4* hv = (const float4*)(o3 + (size_t)n * 24);
#pragma unroll
    for (int q = 0; q < 6; ++q) {
        float4 v = hv[q];
        h[4*q+0] = v.x; h[4*q+1] = v.y; h[4*q+2] = v.z; h[4*q+3] = v.w;
    }
    float acc[12];
#pragma unroll
    for (int j = 0; j < 12; ++j) acc[j] = b2[j];
    for (int k = 0; k < 120; ++k) {
        float t = b1[k];
#pragma unroll
        for (int i = 0; i < 24; ++i) t += h[i] * w1[i * 120 + k];
        t = fmaxf(t, 0.f);
#pragma unroll
        for (int j = 0; j < 12; ++j) acc[j] += t * w2[k * 12 + j];
    }
    float* o = out + (size_t)n * 12;
#pragma unroll
    for (int j = 0; j < 12; ++j) o[j] = acc[j];
}

// ---------------- host launch ----------------
static inline size_t align_up(size_t v, size_t a) { return (v + a - 1) & ~(a - 1); }

extern "C" void kernel_launch(void* const* d_in, const int* in_sizes, int n_in,
                              void* d_out, int out_size, void* d_ws, size_t ws_size,
                              hipStream_t stream)
{
    (void)in_sizes; (void)n_in; (void)out_size; (void)ws_size;

    const float* x    = (const float*)d_in[0];
    const int*  edge  = (const int*)d_in[1];
    const int*  esrc  = edge;
    const int*  edst  = edge + N_EDGES;
    const float* enc_w1 = (const float*)d_in[2];
    const float* enc_b1 = (const float*)d_in[3];
    const float* enc_w2 = (const float*)d_in[4];
    const float* enc_b2 = (const float*)d_in[5];
    const float* s1_wl = (const float*)d_in[6];
    const float* s1_bl = (const float*)d_in[7];
    const float* s1_wr = (const float*)d_in[8];
    const float* s2_wl = (const float*)d_in[9];
    const float* s2_bl = (const float*)d_in[10];
    const float* s2_wr = (const float*)d_in[11];
    const float* s3_wl = (const float*)d_in[12];
    const float* s3_bl = (const float*)d_in[13];
    const float* s3_wr = (const float*)d_in[14];
    const float* dec_w1 = (const float*)d_in[15];
    const float* dec_b1 = (const float*)d_in[16];
    const float* dec_w2 = (const float*)d_in[17];
    const float* dec_b2 = (const float*)d_in[18];
    float* out = (float*)d_out;

    // workspace carve
    char* base = (char*)d_ws;
    size_t off = 0;
    auto carve = [&](size_t bytes) { size_t o = off; off = align_up(off + bytes, 256); return (void*)(base + o); };
    // stage region (35.2MB); dead after k_fill_enc -> o3 (9.6MB) aliases it
    char* stage_region = (char*)carve((size_t)N_BUCKETS * STAGE_CAP * sizeof(unsigned));
    unsigned* stage = (unsigned*)stage_region;
    float* o3       = (float*)stage_region;
    int*   csr      = (int*)carve((size_t)N_BUCKETS * BUCKET_CAP * sizeof(int));          // 28MB
    unsigned* Ptab  = (unsigned*)carve((size_t)(N_NODES + 1) * PROW * sizeof(unsigned));  // 3.2MB
    float* Qtab     = (float*)carve((size_t)N_NODES * 24 * sizeof(float));                // 9.6MB
    unsigned short* h0b = (unsigned short*)carve((size_t)N_NODES * BROW * sizeof(unsigned short));
    unsigned short* h1b = (unsigned short*)carve((size_t)N_NODES * BROW * sizeof(unsigned short));
    unsigned short* pb2 = (unsigned short*)carve((size_t)N_NODES * BROW * sizeof(unsigned short));
    unsigned short* pb3 = (unsigned short*)carve((size_t)N_NODES * BROW * sizeof(unsigned short));
    int*   deg     = (int*)  carve((size_t)N_NODES * sizeof(int));
    float* recip   = (float*)carve((size_t)N_NODES * sizeof(float));
    int*   row_ptr = (int*)  carve((size_t)N_NODES * sizeof(int));
    int*   cursor  = (int*)  carve((size_t)N_BUCKETS * 16 * sizeof(int));
    float* w1t     = (float*)carve((size_t)240 * 32 * sizeof(float));

    const int NB_N = (N_NODES + 255) / 256;      // 391
    const int NB8  = (N_NODES * 8 + 255) / 256;  // 3125

    k_prep<<<30, 256, 0, stream>>>(enc_w1, w1t, cursor);
    k_stage1<<<STAGE_BLOCKS, 256, 0, stream>>>(esrc, edst, cursor, stage);

    // MERGED: fillcsr (391 blocks) + encoder split-K x4 partials (1564 blocks)
    k_fill_enc<<<NB_N * 5, 256, 0, stream>>>(
        stage, cursor, csr, deg, recip, row_ptr,
        x, w1t, enc_b1, enc_w2, h0b, h1b, pb2, pb3);

    // fused encoder-finalize (4 partials) + layer1 xform
    k_encfin_xform<<<NB_N, 256, 0, stream>>>(h0b, h1b, pb2, pb3, enc_b2, s1_wl, s1_wr, Ptab, Qtab);
    k_agg<true><<<NB8, 256, 0, stream>>>(Ptab, Qtab, row_ptr, deg, recip, csr, s1_bl, h1b);
    // layer 2
    k_xform<<<NB_N, 256, 0, stream>>>(h1b, s2_wl, s2_wr, Ptab, Qtab);
    k_agg<true><<<NB8, 256, 0, stream>>>(Ptab, Qtab, row_ptr, deg, recip, csr, s2_bl, h0b);
    // layer 3 (fp32 out, o3 aliases dead stage region) + decoder
    k_xform<<<NB_N, 256, 0, stream>>>(h0b, s3_wl, s3_wr, Ptab, Qtab);
    k_agg3<<<NB8, 256, 0, stream>>>(Ptab, Qtab, row_ptr, deg, recip, csr, s3_bl, o3);
    k_decoder<<<NB_N, 256, 0, stream>>>(o3, dec_w1, dec_b1, dec_w2, dec_b2, out);
}